// Round 23
// baseline (273.237 us; speedup 1.0000x reference)
//
#include <hip/hip_runtime.h>

#define HIDDEN 2048
#define NH 16
#define NKV 4
#define HD 128
#define Bb 2
#define Ss 2048
#define TOK 4096           // Bb*Ss
#define KVD 512            // NKV*HD
#define LOG2E 1.4426950408889634f
#define QSCALE (0.08838834764831845f * 1.4426950408889634f)   // log2e/sqrt(128)
#define DEFER 11.54f       // 8 nats in log2 units

typedef short short8 __attribute__((ext_vector_type(8)));
typedef float f32x4 __attribute__((ext_vector_type(4)));
typedef float f32x16 __attribute__((ext_vector_type(16)));
typedef unsigned int uint4v __attribute__((ext_vector_type(4)));

#define AS1 __attribute__((address_space(1)))
#define AS3 __attribute__((address_space(3)))

#define BARRIER() asm volatile("s_barrier" ::: "memory")
#define WAITV8()  asm volatile("s_waitcnt vmcnt(8)" ::: "memory")
#define WAITV0()  asm volatile("s_waitcnt vmcnt(0)" ::: "memory")

__device__ __forceinline__ float exp2fast(float x){ return __builtin_amdgcn_exp2f(x); }

__device__ __forceinline__ float bf2f(unsigned short u){
  union { unsigned int i; float f; } x; x.i = ((unsigned int)u) << 16; return x.f;
}
__device__ __forceinline__ unsigned short f2bf(float f){
  union { float f; unsigned int i; } x; x.f = f;
  unsigned int r = x.i + 0x7FFFu + ((x.i >> 16) & 1u);   // RNE
  return (unsigned short)(r >> 16);
}
// pack 2 f32 -> 2 bf16 in one u32 (lo = a, hi = b), RNE
__device__ __forceinline__ unsigned int cvtpk(float a, float b){
  unsigned int r;
  asm("v_cvt_pk_bf16_f32 %0, %1, %2" : "=v"(r) : "v"(a), "v"(b));
  return r;
}
__device__ __forceinline__ void gld_lds16(const void* g, void* l){
  __builtin_amdgcn_global_load_lds((const AS1 void*)g, (AS3 void*)l, 16, 0, 0);
}

// ---------------- fused fp32 -> bf16 conversion of all 5 tensors ----------------
#define R0 2097152   // hs  f4 count
#define R1 3145728   // + qw
#define R2 3407872   // + kw
#define R3 3670016   // + vw
#define R4 4718592   // + ow (total)
__global__ void cvt_all(const float* __restrict__ s0, const float* __restrict__ s1,
                        const float* __restrict__ s2, const float* __restrict__ s3,
                        const float* __restrict__ s4, unsigned short* __restrict__ dst){
  int i = blockIdx.x * 256 + threadIdx.x;     // float4 index, grid exact
  const float* src; int off;
  if      (i < R0){ src = s0; off = 0;  }
  else if (i < R1){ src = s1; off = R0; }
  else if (i < R2){ src = s2; off = R1; }
  else if (i < R3){ src = s3; off = R2; }
  else            { src = s4; off = R3; }
  float4 v = reinterpret_cast<const float4*>(src)[i - off];
  ushort4 o;
  o.x = f2bf(v.x); o.y = f2bf(v.y); o.z = f2bf(v.z); o.w = f2bf(v.w);
  reinterpret_cast<ushort4*>(dst)[i] = o;
}

// ---------------- NT GEMM: C[M,N] = A[M,K] * B[N,K]^T (+bias) ----------------
// 128x128 tile, BK=64, double-buffered LDS with counted vmcnt (T3/T4),
// XOR-swizzled LDS. No XCD swizzle (L3-fit working set; swizzle cost ~2%, m160/R16).
// Epilogue regions (merged QKV projection):
//   Cf non-null           -> f32 out at ldc (O-proj path)
//   else col <  2048      -> CbQ bf16, stride 2048, bias qb
//        col <  2560      -> CbK bf16 at col-2048, stride 512, bias kb
//        col >= 2560      -> vT TRANSPOSED at (col-2560)*TOK+row, bias vb
__global__ __launch_bounds__(256, 2) void gemm_nt(
    const unsigned short* __restrict__ A,
    const unsigned short* __restrict__ Bw,
    const float* __restrict__ qb,          // may be null (no bias)
    const float* __restrict__ kb,
    const float* __restrict__ vb,
    unsigned short* __restrict__ CbQ,
    unsigned short* __restrict__ CbK,
    unsigned short* __restrict__ vT,
    float* __restrict__ Cf,                // f32 out (if non-null)
    int M, int N, int K, int ldc)
{
  __shared__ unsigned short lds[2][2][128*64];   // [buf][A|B][row*64 + elem]
  const int tid  = threadIdx.x;
  const int lane = tid & 63;
  const int w  = tid >> 6;          // wave 0..3
  const int wr = w >> 1, wc = w & 1;
  const int row0 = blockIdx.x * 128;
  const int col0 = blockIdx.y * 128;

  const int fr  = lane & 15;
  const int g16 = lane >> 4;
  const int l8  = lane >> 3;        // staging sub-row 0..7
  const int slot = lane & 7;        // staging 16B slot 0..7

  const f32x4 vzero = {0.f, 0.f, 0.f, 0.f};
  f32x4 acc[4][4];
#pragma unroll
  for (int m = 0; m < 4; m++)
#pragma unroll
    for (int n = 0; n < 4; n++) acc[m][n] = vzero;

  // stage one 128x64 K-tile of A and B into lds[buf] (8 gload_lds/thread)
  auto STAGE = [&](int buf, int kt){
#pragma unroll
    for (int i = 0; i < 4; i++){
      int r = w*32 + i*8 + l8;
      gld_lds16(A  + (size_t)(row0 + r)*K + kt*64 + ((slot ^ (r & 7)) << 3),
                &lds[buf][0][w*2048 + i*512 + lane*8]);
    }
#pragma unroll
    for (int i = 0; i < 4; i++){
      int r = w*32 + i*8 + l8;
      gld_lds16(Bw + (size_t)(col0 + r)*K + kt*64 + ((slot ^ (r & 7)) << 3),
                &lds[buf][1][w*2048 + i*512 + lane*8]);
    }
  };

  const int NT = K >> 6;
  STAGE(0, 0);
  STAGE(1, 1);
  WAITV8();            // tile 0 landed (tile 1 still in flight)
  BARRIER();

  for (int kt = 0; kt < NT; kt++){
    const int cur = kt & 1;
    const unsigned short* Al = &lds[cur][0][0];
    const unsigned short* Bl = &lds[cur][1][0];
#pragma unroll
    for (int ks = 0; ks < 2; ks++){
      short8 af[4], bf[4];
#pragma unroll
      for (int m = 0; m < 4; m++){
        int r = wr*64 + m*16 + fr;
        af[m] = *(const short8*)&Al[r*64 + (((ks*4 + g16) ^ (r & 7)) << 3)];
      }
#pragma unroll
      for (int n = 0; n < 4; n++){
        int r = wc*64 + n*16 + fr;
        bf[n] = *(const short8*)&Bl[r*64 + (((ks*4 + g16) ^ (r & 7)) << 3)];
      }
      __builtin_amdgcn_s_setprio(1);
#pragma unroll
      for (int m = 0; m < 4; m++)
#pragma unroll
        for (int n = 0; n < 4; n++)
          acc[m][n] = __builtin_amdgcn_mfma_f32_16x16x32_bf16(af[m], bf[n], acc[m][n], 0, 0, 0);
      __builtin_amdgcn_s_setprio(0);
    }
    if (kt == NT - 1) break;
    BARRIER();                       // all waves done reading lds[cur]
    if (kt + 2 < NT){
      STAGE(cur, kt + 2);            // refill the buffer just consumed
      WAITV8();                      // tile kt+1's 8 loads complete (kt+2's stay in flight)
    } else {
      WAITV0();                      // last tile's loads complete
    }
    BARRIER();                       // writes visible to all waves
  }

  const int rr = g16 * 4;
#pragma unroll
  for (int n = 0; n < 4; n++){
    int col = col0 + wc*64 + n*16 + fr;
    float bv = 0.f;
    if (qb) bv = (col < 2048) ? qb[col] : (col < 2560 ? kb[col - 2048] : vb[col - 2560]);
    if (Cf){
#pragma unroll
      for (int m = 0; m < 4; m++){
        int row = row0 + wr*64 + m*16 + rr;
#pragma unroll
        for (int r = 0; r < 4; r++)
          Cf[(size_t)(row + r) * ldc + col] = acc[m][n][r] + bv;
      }
    } else if (col < 2048){
#pragma unroll
      for (int m = 0; m < 4; m++){
        int row = row0 + wr*64 + m*16 + rr;
#pragma unroll
        for (int r = 0; r < 4; r++)
          CbQ[(size_t)(row + r) * 2048 + col] = f2bf(acc[m][n][r] + bv);
      }
    } else if (col < 2560){
      int ck = col - 2048;
#pragma unroll
      for (int m = 0; m < 4; m++){
        int row = row0 + wr*64 + m*16 + rr;
#pragma unroll
        for (int r = 0; r < 4; r++)
          CbK[(size_t)(row + r) * 512 + ck] = f2bf(acc[m][n][r] + bv);
      }
    } else {
      int cv = col - 2560;
#pragma unroll
      for (int m = 0; m < 4; m++){
        int row = row0 + wr*64 + m*16 + rr;
        ushort4 pk;
        pk.x = f2bf(acc[m][n][0] + bv); pk.y = f2bf(acc[m][n][1] + bv);
        pk.z = f2bf(acc[m][n][2] + bv); pk.w = f2bf(acc[m][n][3] + bv);
        *reinterpret_cast<ushort4*>(&vT[(size_t)cv * TOK + row]) = pk;
      }
    }
  }
}

// ---------------- RoPE (in-place; q scaled by log2e/sqrt(D)) ----------------
__global__ void rope_kernel(unsigned short* __restrict__ q, unsigned short* __restrict__ k,
                            const int* __restrict__ pos,
                            const float* __restrict__ cosT, const float* __restrict__ sinT)
{
  int idx = blockIdx.x * blockDim.x + threadIdx.x;
  const int qN = TOK * NH * 64;
  if (idx < qN){
    int d  = idx & 63;
    int hh = (idx >> 6) & (NH - 1);
    int t  = idx >> 10;
    int p  = pos[t & (Ss - 1)];
    float c = cosT[p * HD + d], s = sinT[p * HD + d];
    unsigned short* base = q + (size_t)t * HIDDEN + hh * HD;
    float lo = bf2f(base[d]), hi = bf2f(base[d + 64]);
    base[d]      = f2bf((lo * c - hi * s) * QSCALE);
    base[d + 64] = f2bf((hi * c + lo * s) * QSCALE);
  } else {
    int j  = idx - qN;
    int d  = j & 63;
    int hh = (j >> 6) & (NKV - 1);
    int t  = j >> 8;
    int p  = pos[t & (Ss - 1)];
    float c = cosT[p * HD + d], s = sinT[p * HD + d];
    unsigned short* base = k + (size_t)t * KVD + hh * HD;
    float lo = bf2f(base[d]), hi = bf2f(base[d + 64]);
    base[d]      = f2bf(lo * c - hi * s);
    base[d + 64] = f2bf(hi * c + lo * s);
  }
}

// ---------------- Flash attention: swapped-QK 32x32 in-register softmax ----------------
// grid (64,4,2) = 512 blocks; 256 threads = 4 waves = 4 heads x one 32-row q-subtile.
// K/V staged via global_load_lds (pre-swizzled global src, linear LDS dest, rule #21).
// launch_bounds(256,3): unified reg budget 170 (arch ~106 + 64 acc) -> 3 waves/SIMD.
// pk[] array eliminated: each cvtpk pair consumed by exactly one pa[ks] (smaller live set).
__global__ __launch_bounds__(256, 3) void attn_kernel(
    const unsigned short* __restrict__ Q,    // [TOK][HIDDEN], post-RoPE, pre-scaled
    const unsigned short* __restrict__ Kb,   // [TOK][KVD]
    const unsigned short* __restrict__ Vt,   // V^T [KVD][TOK]
    const float* __restrict__ mask,          // [Bb][Ss]
    unsigned short* __restrict__ O)          // [TOK][HIDDEN]
{
  __shared__ unsigned short Klds[64*128];    // [k][16B-slot], slot stores global slot^(k&7)
  __shared__ unsigned short Vlds[128*64];    // V^T [d][8 slots], slot stores global slot^(d&7)

  const int tid = threadIdx.x, lane = tid & 63, wid = tid >> 6;
  const int qt = blockIdx.x, kvh = blockIdx.y, b = blockIdx.z;
  const int head = kvh*4 + wid;
  const int q0 = lane & 31;          // this lane's q-row (softmax) / d-col (PV out)
  const int h  = lane >> 5;          // half-wave id
  const int tokQ = b*Ss + qt*32;

  // Q fragments in registers: 8 d-slots of 16 (B-frag: col=q0, k-elems h*8..h*8+7)
  short8 qf[8];
#pragma unroll
  for (int ds = 0; ds < 8; ds++)
    qf[ds] = *(const short8*)(Q + (size_t)(tokQ + q0)*HIDDEN + head*HD + ds*16 + h*8);

  f32x16 oacc[4];
#pragma unroll
  for (int dblk = 0; dblk < 4; dblk++)
#pragma unroll
    for (int r = 0; r < 16; r++) oacc[dblk][r] = 0.f;
  float mrow = -1e30f, lrow = 0.f;

  const float* maskrow = mask + b*Ss;

  // staging lane geometry: K: 4 rows x 16 slots per wave-call; V^T: 8 rows x 8 slots
  const int krow_l = lane >> 4, kslot = lane & 15;
  const int vrow_l = lane >> 3, vslot = lane & 7;

  const size_t kgbase = (size_t)(b*Ss)*KVD + (size_t)kvh*HD;
  const size_t vgbase = (size_t)(kvh*HD)*TOK + (size_t)(b*Ss);

  const int NT = Ss/64;
  for (int kt = 0; kt < NT; kt++){
    if (kt) __syncthreads();       // all reads of LDS done before overwrite
    const int tok = kt*64;
    // async stage: per-lane swizzled global addr, wave-uniform linear LDS dest
#pragma unroll
    for (int i = 0; i < 4; i++){
      int kr = wid*16 + i*4 + krow_l;
      gld_lds16(Kb + kgbase + (size_t)(tok + kr)*KVD + ((kslot ^ (kr & 7)) << 3),
                &Klds[(wid*16 + i*4)*128]);
      int vr = wid*32 + i*8 + vrow_l;
      gld_lds16(Vt + vgbase + (size_t)vr*TOK + tok + ((vslot ^ (vr & 7)) << 3),
                &Vlds[(wid*32 + i*8)*64]);
    }
    __syncthreads();               // vmcnt(0) drain + barrier: tile visible

    // ---- S^T = K * Q^T : two 32x32 outputs (k-tiles t=0,1), chained over 8 d-slots
    f32x16 st0, st1;
#pragma unroll
    for (int r = 0; r < 16; r++){ st0[r] = 0.f; st1[r] = 0.f; }
    __builtin_amdgcn_s_setprio(1);
#pragma unroll
    for (int ds = 0; ds < 8; ds++){
      short8 kf0 = *(const short8*)&Klds[(q0     )*128 + ((ds*16 + h*8) ^ ((q0 & 7) << 3))];
      short8 kf1 = *(const short8*)&Klds[(32 + q0)*128 + ((ds*16 + h*8) ^ ((q0 & 7) << 3))];
      st0 = __builtin_amdgcn_mfma_f32_32x32x16_bf16(kf0, qf[ds], st0, 0, 0, 0);
      st1 = __builtin_amdgcn_mfma_f32_32x32x16_bf16(kf1, qf[ds], st1, 0, 0, 0);
    }
    __builtin_amdgcn_s_setprio(0);

    // ---- mask add (log2 domain); p[t*16+reg], k = 32t + (reg&3)+8*(reg>>2)+4h
    float p[32];
#pragma unroll
    for (int g2 = 0; g2 < 4; g2++){
      f32x4 m0 = *(const f32x4*)(maskrow + kt*64      + g2*8 + h*4);
      f32x4 m1 = *(const f32x4*)(maskrow + kt*64 + 32 + g2*8 + h*4);
#pragma unroll
      for (int r = 0; r < 4; r++){
        p[g2*4 + r]      = st0[g2*4 + r] + m0[r] * LOG2E;
        p[16 + g2*4 + r] = st1[g2*4 + r] + m1[r] * LOG2E;
      }
    }

    // ---- online softmax (in-register; row is lane-local, 1 cross-lane op)
    float vmax = p[0];
#pragma unroll
    for (int i = 1; i < 32; i++) vmax = fmaxf(vmax, p[i]);
    vmax = fmaxf(vmax, __shfl_xor(vmax, 32));
    if (__any(vmax > mrow + DEFER)){
      float mnew = fmaxf(mrow, vmax);
      float sc = exp2fast(mrow - mnew);
      mrow = mnew; lrow *= sc;
#pragma unroll
      for (int reg = 0; reg < 16; reg++){
        float scr = __shfl(sc, (reg & 3) + 8*(reg >> 2) + 4*h);
#pragma unroll
        for (int dblk = 0; dblk < 4; dblk++) oacc[dblk][reg] *= scr;
      }
    }
    float rs = 0.f;
#pragma unroll
    for (int i = 0; i < 32; i++){ p[i] = exp2fast(p[i] - mrow); rs += p[i]; }
    rs += __shfl_xor(rs, 32);
    lrow += rs;

    // ---- pack P to bf16 + build PV A-frags: cvtpk computed in-loop (no pk[] array)
    short8 pa[4];
#pragma unroll
    for (int ks = 0; ks < 4; ks++){
      const int ia = 4*(ks >> 1) + 2*(ks & 1);
      unsigned int A0 = cvtpk(p[ia*4 + 0], p[ia*4 + 1]);
      unsigned int A1 = cvtpk(p[ia*4 + 2], p[ia*4 + 3]);
      unsigned int B0 = cvtpk(p[ia*4 + 4], p[ia*4 + 5]);
      unsigned int B1 = cvtpk(p[ia*4 + 6], p[ia*4 + 7]);
      unsigned int s0 = h ? A0 : B0, s1 = h ? A1 : B1;
      unsigned int r0 = (unsigned int)__shfl_xor((int)s0, 32);
      unsigned int r1 = (unsigned int)__shfl_xor((int)s1, 32);
      uint4v wv = { h ? r0 : A0, h ? r1 : A1, h ? B0 : r0, h ? B1 : r1 };
      pa[ks] = __builtin_bit_cast(short8, wv);
    }

    // ---- O += P * V  (A = pa[ks], B = V^T fragments from LDS)
    __builtin_amdgcn_s_setprio(1);
#pragma unroll
    for (int dblk = 0; dblk < 4; dblk++){
#pragma unroll
      for (int ks = 0; ks < 4; ks++){
        short8 vb = *(const short8*)&Vlds[(dblk*32 + q0)*64 + ((ks*16 + h*8) ^ ((q0 & 7) << 3))];
        oacc[dblk] = __builtin_amdgcn_mfma_f32_32x32x16_bf16(pa[ks], vb, oacc[dblk], 0, 0, 0);
      }
    }
    __builtin_amdgcn_s_setprio(0);
  }

  // ---- epilogue: O[q = crow(reg,h)][d = dblk*32 + q0]
  float inv = 1.0f / lrow;
#pragma unroll
  for (int reg = 0; reg < 16; reg++){
    const int crow = (reg & 3) + 8*(reg >> 2) + 4*h;
    float invr = __shfl(inv, crow);
    int row = tokQ + crow;
#pragma unroll
    for (int dblk = 0; dblk < 4; dblk++)
      O[(size_t)row*HIDDEN + head*HD + dblk*32 + q0] = f2bf(oacc[dblk][reg] * invr);
  }
}

// ---------------- launcher ----------------
extern "C" void kernel_launch(void* const* d_in, const int* in_sizes, int n_in,
                              void* d_out, int out_size, void* d_ws, size_t ws_size,
                              hipStream_t stream)
{
  (void)in_sizes; (void)n_in; (void)out_size; (void)ws_size;
  const float* hs   = (const float*)d_in[0];
  const float* mask = (const float*)d_in[1];
  const int*   pos  = (const int*)d_in[2];
  const float* qw   = (const float*)d_in[3];
  const float* qb   = (const float*)d_in[4];
  const float* kw   = (const float*)d_in[5];
  const float* kb   = (const float*)d_in[6];
  const float* vw   = (const float*)d_in[7];
  const float* vb   = (const float*)d_in[8];
  const float* ow   = (const float*)d_in[9];
  const float* cosT = (const float*)d_in[10];
  const float* sinT = (const float*)d_in[11];
  float* out = (float*)d_out;

  unsigned short* ws  = (unsigned short*)d_ws;
  unsigned short* hsB = ws;                                   // [4096][2048]
  unsigned short* qwB = hsB + (size_t)TOK * HIDDEN;           // [2048][2048] (qwB|kwB|vwB contiguous)
  unsigned short* kwB = qwB + (size_t)HIDDEN * HIDDEN;        // [512][2048]
  unsigned short* vwB = kwB + (size_t)KVD * HIDDEN;           // [512][2048]
  unsigned short* owB = vwB + (size_t)KVD * HIDDEN;           // [2048][2048]
  unsigned short* qB  = owB + (size_t)HIDDEN * HIDDEN;        // [4096][2048]
  unsigned short* kB  = qB  + (size_t)TOK * HIDDEN;           // [4096][512]
  unsigned short* vTB = kB  + (size_t)TOK * KVD;              // [512][4096]  V transposed
  unsigned short* aoB = vTB + (size_t)KVD * TOK;              // [4096][2048]
  (void)vwB;

  // one fused conversion pass (dst = ws prefix, contiguous & in order)
  cvt_all<<<R4 / 256, 256, 0, stream>>>(hs, qw, kw, vw, ow, ws);

  // merged QKV projection: N=3072 (B = qwB|kwB|vwB contiguous); epilogue routes
  // col<2048 -> qB, col<2560 -> kB, else -> vTB (transposed)
  gemm_nt<<<dim3(TOK/128, 3072/128), 256, 0, stream>>>(
      hsB, qwB, qb, kb, vb, qB, kB, vTB, nullptr, TOK, 3072, HIDDEN, 0);

  // RoPE (q scaled by log2e/sqrt(D); k in [TOK][512] layout)
  {
    int total = TOK * NH * 64 + TOK * NKV * 64;
    rope_kernel<<<total / 256, 256, 0, stream>>>(qB, kB, pos, cosT, sinT);
  }

  // attention: 512 blocks x 256 threads, gld_lds-staged K/V, 3 waves/SIMD target
  attn_kernel<<<dim3(Ss/32, NKV, Bb), 256, 0, stream>>>(qB, kB, vTB, mask, aoB);

  // output projection -> fp32 d_out
  gemm_nt<<<dim3(TOK/128, HIDDEN/128), 256, 0, stream>>>(
      aoB, owB, nullptr, nullptr, nullptr, nullptr, nullptr, nullptr, out, TOK, HIDDEN, HIDDEN, HIDDEN);
}

// Round 24
// 215.970 us; speedup vs baseline: 1.2652x; 1.2652x over previous
//
#include <hip/hip_runtime.h>

#define HIDDEN 2048
#define NH 16
#define NKV 4
#define HD 128
#define Bb 2
#define Ss 2048
#define TOK 4096           // Bb*Ss
#define KVD 512            // NKV*HD
#define LOG2E 1.4426950408889634f
#define QSCALE (0.08838834764831845f * 1.4426950408889634f)   // log2e/sqrt(128)
#define DEFER 11.54f       // 8 nats in log2 units

typedef short short8 __attribute__((ext_vector_type(8)));
typedef float f32x4 __attribute__((ext_vector_type(4)));
typedef float f32x16 __attribute__((ext_vector_type(16)));
typedef unsigned int uint4v __attribute__((ext_vector_type(4)));

#define AS1 __attribute__((address_space(1)))
#define AS3 __attribute__((address_space(3)))

#define BARRIER() asm volatile("s_barrier" ::: "memory")
#define WAITV8()  asm volatile("s_waitcnt vmcnt(8)" ::: "memory")
#define WAITV0()  asm volatile("s_waitcnt vmcnt(0)" ::: "memory")

__device__ __forceinline__ float exp2fast(float x){ return __builtin_amdgcn_exp2f(x); }

__device__ __forceinline__ float bf2f(unsigned short u){
  union { unsigned int i; float f; } x; x.i = ((unsigned int)u) << 16; return x.f;
}
__device__ __forceinline__ unsigned short f2bf(float f){
  union { float f; unsigned int i; } x; x.f = f;
  unsigned int r = x.i + 0x7FFFu + ((x.i >> 16) & 1u);   // RNE
  return (unsigned short)(r >> 16);
}
// pack 2 f32 -> 2 bf16 in one u32 (lo = a, hi = b), RNE
__device__ __forceinline__ unsigned int cvtpk(float a, float b){
  unsigned int r;
  asm("v_cvt_pk_bf16_f32 %0, %1, %2" : "=v"(r) : "v"(a), "v"(b));
  return r;
}
__device__ __forceinline__ void gld_lds16(const void* g, void* l){
  __builtin_amdgcn_global_load_lds((const AS1 void*)g, (AS3 void*)l, 16, 0, 0);
}

// ---------------- fused fp32 -> bf16 conversion of all 5 tensors ----------------
#define R0 2097152   // hs  f4 count
#define R1 3145728   // + qw
#define R2 3407872   // + kw
#define R3 3670016   // + vw
#define R4 4718592   // + ow (total)
__global__ void cvt_all(const float* __restrict__ s0, const float* __restrict__ s1,
                        const float* __restrict__ s2, const float* __restrict__ s3,
                        const float* __restrict__ s4, unsigned short* __restrict__ dst){
  int i = blockIdx.x * 256 + threadIdx.x;     // float4 index, grid exact
  const float* src; int off;
  if      (i < R0){ src = s0; off = 0;  }
  else if (i < R1){ src = s1; off = R0; }
  else if (i < R2){ src = s2; off = R1; }
  else if (i < R3){ src = s3; off = R2; }
  else            { src = s4; off = R3; }
  float4 v = reinterpret_cast<const float4*>(src)[i - off];
  ushort4 o;
  o.x = f2bf(v.x); o.y = f2bf(v.y); o.z = f2bf(v.z); o.w = f2bf(v.w);
  reinterpret_cast<ushort4*>(dst)[i] = o;
}

// ---------------- NT GEMM: C[M,N] = A[M,K] * B[N,K]^T (+bias) ----------------
// 128x128 tile, BK=64, double-buffered LDS with counted vmcnt (T3/T4),
// XOR-swizzled LDS. No XCD swizzle (L3-fit working set; swizzle cost ~2%, m160/R16).
// Epilogue regions (merged QKV projection):
//   Cf non-null           -> f32 out at ldc (O-proj path)
//   else col <  2048      -> CbQ bf16, stride 2048, bias qb
//        col <  2560      -> CbK bf16 at col-2048, stride 512, bias kb
//        col >= 2560      -> vT TRANSPOSED at (col-2560)*TOK+row, bias vb
__global__ __launch_bounds__(256, 2) void gemm_nt(
    const unsigned short* __restrict__ A,
    const unsigned short* __restrict__ Bw,
    const float* __restrict__ qb,          // may be null (no bias)
    const float* __restrict__ kb,
    const float* __restrict__ vb,
    unsigned short* __restrict__ CbQ,
    unsigned short* __restrict__ CbK,
    unsigned short* __restrict__ vT,
    float* __restrict__ Cf,                // f32 out (if non-null)
    int M, int N, int K, int ldc)
{
  __shared__ unsigned short lds[2][2][128*64];   // [buf][A|B][row*64 + elem]
  const int tid  = threadIdx.x;
  const int lane = tid & 63;
  const int w  = tid >> 6;          // wave 0..3
  const int wr = w >> 1, wc = w & 1;
  const int row0 = blockIdx.x * 128;
  const int col0 = blockIdx.y * 128;

  const int fr  = lane & 15;
  const int g16 = lane >> 4;
  const int l8  = lane >> 3;        // staging sub-row 0..7
  const int slot = lane & 7;        // staging 16B slot 0..7

  const f32x4 vzero = {0.f, 0.f, 0.f, 0.f};
  f32x4 acc[4][4];
#pragma unroll
  for (int m = 0; m < 4; m++)
#pragma unroll
    for (int n = 0; n < 4; n++) acc[m][n] = vzero;

  // stage one 128x64 K-tile of A and B into lds[buf] (8 gload_lds/thread)
  auto STAGE = [&](int buf, int kt){
#pragma unroll
    for (int i = 0; i < 4; i++){
      int r = w*32 + i*8 + l8;
      gld_lds16(A  + (size_t)(row0 + r)*K + kt*64 + ((slot ^ (r & 7)) << 3),
                &lds[buf][0][w*2048 + i*512 + lane*8]);
    }
#pragma unroll
    for (int i = 0; i < 4; i++){
      int r = w*32 + i*8 + l8;
      gld_lds16(Bw + (size_t)(col0 + r)*K + kt*64 + ((slot ^ (r & 7)) << 3),
                &lds[buf][1][w*2048 + i*512 + lane*8]);
    }
  };

  const int NT = K >> 6;
  STAGE(0, 0);
  STAGE(1, 1);
  WAITV8();            // tile 0 landed (tile 1 still in flight)
  BARRIER();

  for (int kt = 0; kt < NT; kt++){
    const int cur = kt & 1;
    const unsigned short* Al = &lds[cur][0][0];
    const unsigned short* Bl = &lds[cur][1][0];
#pragma unroll
    for (int ks = 0; ks < 2; ks++){
      short8 af[4], bf[4];
#pragma unroll
      for (int m = 0; m < 4; m++){
        int r = wr*64 + m*16 + fr;
        af[m] = *(const short8*)&Al[r*64 + (((ks*4 + g16) ^ (r & 7)) << 3)];
      }
#pragma unroll
      for (int n = 0; n < 4; n++){
        int r = wc*64 + n*16 + fr;
        bf[n] = *(const short8*)&Bl[r*64 + (((ks*4 + g16) ^ (r & 7)) << 3)];
      }
      __builtin_amdgcn_s_setprio(1);
#pragma unroll
      for (int m = 0; m < 4; m++)
#pragma unroll
        for (int n = 0; n < 4; n++)
          acc[m][n] = __builtin_amdgcn_mfma_f32_16x16x32_bf16(af[m], bf[n], acc[m][n], 0, 0, 0);
      __builtin_amdgcn_s_setprio(0);
    }
    if (kt == NT - 1) break;
    BARRIER();                       // all waves done reading lds[cur]
    if (kt + 2 < NT){
      STAGE(cur, kt + 2);            // refill the buffer just consumed
      WAITV8();                      // tile kt+1's 8 loads complete (kt+2's stay in flight)
    } else {
      WAITV0();                      // last tile's loads complete
    }
    BARRIER();                       // writes visible to all waves
  }

  const int rr = g16 * 4;
#pragma unroll
  for (int n = 0; n < 4; n++){
    int col = col0 + wc*64 + n*16 + fr;
    float bv = 0.f;
    if (qb) bv = (col < 2048) ? qb[col] : (col < 2560 ? kb[col - 2048] : vb[col - 2560]);
    if (Cf){
#pragma unroll
      for (int m = 0; m < 4; m++){
        int row = row0 + wr*64 + m*16 + rr;
#pragma unroll
        for (int r = 0; r < 4; r++)
          Cf[(size_t)(row + r) * ldc + col] = acc[m][n][r] + bv;
      }
    } else if (col < 2048){
#pragma unroll
      for (int m = 0; m < 4; m++){
        int row = row0 + wr*64 + m*16 + rr;
#pragma unroll
        for (int r = 0; r < 4; r++)
          CbQ[(size_t)(row + r) * 2048 + col] = f2bf(acc[m][n][r] + bv);
      }
    } else if (col < 2560){
      int ck = col - 2048;
#pragma unroll
      for (int m = 0; m < 4; m++){
        int row = row0 + wr*64 + m*16 + rr;
#pragma unroll
        for (int r = 0; r < 4; r++)
          CbK[(size_t)(row + r) * 512 + ck] = f2bf(acc[m][n][r] + bv);
      }
    } else {
      int cv = col - 2560;
#pragma unroll
      for (int m = 0; m < 4; m++){
        int row = row0 + wr*64 + m*16 + rr;
        ushort4 pk;
        pk.x = f2bf(acc[m][n][0] + bv); pk.y = f2bf(acc[m][n][1] + bv);
        pk.z = f2bf(acc[m][n][2] + bv); pk.w = f2bf(acc[m][n][3] + bv);
        *reinterpret_cast<ushort4*>(&vT[(size_t)cv * TOK + row]) = pk;
      }
    }
  }
}

// ---------------- RoPE (in-place; q scaled by log2e/sqrt(D)) ----------------
__global__ void rope_kernel(unsigned short* __restrict__ q, unsigned short* __restrict__ k,
                            const int* __restrict__ pos,
                            const float* __restrict__ cosT, const float* __restrict__ sinT)
{
  int idx = blockIdx.x * blockDim.x + threadIdx.x;
  const int qN = TOK * NH * 64;
  if (idx < qN){
    int d  = idx & 63;
    int hh = (idx >> 6) & (NH - 1);
    int t  = idx >> 10;
    int p  = pos[t & (Ss - 1)];
    float c = cosT[p * HD + d], s = sinT[p * HD + d];
    unsigned short* base = q + (size_t)t * HIDDEN + hh * HD;
    float lo = bf2f(base[d]), hi = bf2f(base[d + 64]);
    base[d]      = f2bf((lo * c - hi * s) * QSCALE);
    base[d + 64] = f2bf((hi * c + lo * s) * QSCALE);
  } else {
    int j  = idx - qN;
    int d  = j & 63;
    int hh = (j >> 6) & (NKV - 1);
    int t  = j >> 8;
    int p  = pos[t & (Ss - 1)];
    float c = cosT[p * HD + d], s = sinT[p * HD + d];
    unsigned short* base = k + (size_t)t * KVD + hh * HD;
    float lo = bf2f(base[d]), hi = bf2f(base[d + 64]);
    base[d]      = f2bf(lo * c - hi * s);
    base[d + 64] = f2bf(hi * c + lo * s);
  }
}

// ---------------- Flash attention: swapped-QK 32x32 in-register softmax ----------------
// grid (64,4,2) = 512 blocks; 256 threads = 4 waves = 4 heads x one 32-row q-subtile.
// K/V staged via global_load_lds: pre-swizzled GLOBAL source + linear LDS dest +
// swizzled read (rule #21). Natural regs (~116 arch + 64 acc = 180 unified -> 2 waves/SIMD;
// forcing 3 waves spills, measured R11/R23).
__global__ __launch_bounds__(256, 2) void attn_kernel(
    const unsigned short* __restrict__ Q,    // [TOK][HIDDEN], post-RoPE, pre-scaled
    const unsigned short* __restrict__ Kb,   // [TOK][KVD]
    const unsigned short* __restrict__ Vt,   // V^T [KVD][TOK]
    const float* __restrict__ mask,          // [Bb][Ss]
    unsigned short* __restrict__ O)          // [TOK][HIDDEN]
{
  __shared__ unsigned short Klds[64*128];    // [k][16B-slot], slot stores global slot^(k&7)
  __shared__ unsigned short Vlds[128*64];    // V^T [d][8 slots], slot stores global slot^(d&7)

  const int tid = threadIdx.x, lane = tid & 63, wid = tid >> 6;
  const int qt = blockIdx.x, kvh = blockIdx.y, b = blockIdx.z;
  const int head = kvh*4 + wid;
  const int q0 = lane & 31;          // this lane's q-row (softmax) / d-col (PV out)
  const int h  = lane >> 5;          // half-wave id
  const int tokQ = b*Ss + qt*32;

  // Q fragments in registers: 8 d-slots of 16 (B-frag: col=q0, k-elems h*8..h*8+7)
  short8 qf[8];
#pragma unroll
  for (int ds = 0; ds < 8; ds++)
    qf[ds] = *(const short8*)(Q + (size_t)(tokQ + q0)*HIDDEN + head*HD + ds*16 + h*8);

  f32x16 oacc[4];
#pragma unroll
  for (int dblk = 0; dblk < 4; dblk++)
#pragma unroll
    for (int r = 0; r < 16; r++) oacc[dblk][r] = 0.f;
  float mrow = -1e30f, lrow = 0.f;

  const float* maskrow = mask + b*Ss;

  // staging lane geometry: K: 4 rows x 16 slots per wave-call; V^T: 8 rows x 8 slots
  const int krow_l = lane >> 4, kslot = lane & 15;
  const int vrow_l = lane >> 3, vslot = lane & 7;

  const size_t kgbase = (size_t)(b*Ss)*KVD + (size_t)kvh*HD;
  const size_t vgbase = (size_t)(kvh*HD)*TOK + (size_t)(b*Ss);

  const int NT = Ss/64;
  for (int kt = 0; kt < NT; kt++){
    if (kt) __syncthreads();       // all reads of LDS done before overwrite
    const int tok = kt*64;
    // async stage: per-lane swizzled global addr, wave-uniform linear LDS dest
#pragma unroll
    for (int i = 0; i < 4; i++){
      int kr = wid*16 + i*4 + krow_l;
      gld_lds16(Kb + kgbase + (size_t)(tok + kr)*KVD + ((kslot ^ (kr & 7)) << 3),
                &Klds[(wid*16 + i*4)*128]);
      int vr = wid*32 + i*8 + vrow_l;
      gld_lds16(Vt + vgbase + (size_t)vr*TOK + tok + ((vslot ^ (vr & 7)) << 3),
                &Vlds[(wid*32 + i*8)*64]);
    }
    __syncthreads();               // vmcnt(0) drain + barrier: tile visible

    // ---- S^T = K * Q^T : two 32x32 outputs (k-tiles t=0,1), chained over 8 d-slots
    f32x16 st0, st1;
#pragma unroll
    for (int r = 0; r < 16; r++){ st0[r] = 0.f; st1[r] = 0.f; }
    __builtin_amdgcn_s_setprio(1);
#pragma unroll
    for (int ds = 0; ds < 8; ds++){
      short8 kf0 = *(const short8*)&Klds[(q0     )*128 + ((ds*16 + h*8) ^ ((q0 & 7) << 3))];
      short8 kf1 = *(const short8*)&Klds[(32 + q0)*128 + ((ds*16 + h*8) ^ ((q0 & 7) << 3))];
      st0 = __builtin_amdgcn_mfma_f32_32x32x16_bf16(kf0, qf[ds], st0, 0, 0, 0);
      st1 = __builtin_amdgcn_mfma_f32_32x32x16_bf16(kf1, qf[ds], st1, 0, 0, 0);
    }
    __builtin_amdgcn_s_setprio(0);

    // ---- mask add (log2 domain); p[t*16+reg], k = 32t + (reg&3)+8*(reg>>2)+4h
    float p[32];
#pragma unroll
    for (int g2 = 0; g2 < 4; g2++){
      f32x4 m0 = *(const f32x4*)(maskrow + kt*64      + g2*8 + h*4);
      f32x4 m1 = *(const f32x4*)(maskrow + kt*64 + 32 + g2*8 + h*4);
#pragma unroll
      for (int r = 0; r < 4; r++){
        p[g2*4 + r]      = st0[g2*4 + r] + m0[r] * LOG2E;
        p[16 + g2*4 + r] = st1[g2*4 + r] + m1[r] * LOG2E;
      }
    }

    // ---- online softmax (in-register; row is lane-local, 1 cross-lane op)
    float vmax = p[0];
#pragma unroll
    for (int i = 1; i < 32; i++) vmax = fmaxf(vmax, p[i]);
    vmax = fmaxf(vmax, __shfl_xor(vmax, 32));
    if (__any(vmax > mrow + DEFER)){
      float mnew = fmaxf(mrow, vmax);
      float sc = exp2fast(mrow - mnew);
      mrow = mnew; lrow *= sc;
#pragma unroll
      for (int reg = 0; reg < 16; reg++){
        float scr = __shfl(sc, (reg & 3) + 8*(reg >> 2) + 4*h);
#pragma unroll
        for (int dblk = 0; dblk < 4; dblk++) oacc[dblk][reg] *= scr;
      }
    }
    float rs = 0.f;
#pragma unroll
    for (int i = 0; i < 32; i++){ p[i] = exp2fast(p[i] - mrow); rs += p[i]; }
    rs += __shfl_xor(rs, 32);
    lrow += rs;

    // ---- pack P to bf16 and build PV A-frags via one shfl_xor(32) exchange
    unsigned int pk[8][2];
#pragma unroll
    for (int G = 0; G < 8; G++){
      pk[G][0] = cvtpk(p[G*4 + 0], p[G*4 + 1]);
      pk[G][1] = cvtpk(p[G*4 + 2], p[G*4 + 3]);
    }
    short8 pa[4];
#pragma unroll
    for (int ks = 0; ks < 4; ks++){
      const int ia = 4*(ks >> 1) + 2*(ks & 1);
      unsigned int A0 = pk[ia][0],   A1 = pk[ia][1];
      unsigned int B0 = pk[ia+1][0], B1 = pk[ia+1][1];
      unsigned int s0 = h ? A0 : B0, s1 = h ? A1 : B1;
      unsigned int r0 = (unsigned int)__shfl_xor((int)s0, 32);
      unsigned int r1 = (unsigned int)__shfl_xor((int)s1, 32);
      uint4v wv = { h ? r0 : A0, h ? r1 : A1, h ? B0 : r0, h ? B1 : r1 };
      pa[ks] = __builtin_bit_cast(short8, wv);
    }

    // ---- O += P * V  (A = pa[ks], B = V^T fragments from LDS)
    __builtin_amdgcn_s_setprio(1);
#pragma unroll
    for (int dblk = 0; dblk < 4; dblk++){
#pragma unroll
      for (int ks = 0; ks < 4; ks++){
        short8 vb = *(const short8*)&Vlds[(dblk*32 + q0)*64 + ((ks*16 + h*8) ^ ((q0 & 7) << 3))];
        oacc[dblk] = __builtin_amdgcn_mfma_f32_32x32x16_bf16(pa[ks], vb, oacc[dblk], 0, 0, 0);
      }
    }
    __builtin_amdgcn_s_setprio(0);
  }

  // ---- epilogue: O[q = crow(reg,h)][d = dblk*32 + q0]
  float inv = 1.0f / lrow;
#pragma unroll
  for (int reg = 0; reg < 16; reg++){
    const int crow = (reg & 3) + 8*(reg >> 2) + 4*h;
    float invr = __shfl(inv, crow);
    int row = tokQ + crow;
#pragma unroll
    for (int dblk = 0; dblk < 4; dblk++)
      O[(size_t)row*HIDDEN + head*HD + dblk*32 + q0] = f2bf(oacc[dblk][reg] * invr);
  }
}

// ---------------- launcher ----------------
extern "C" void kernel_launch(void* const* d_in, const int* in_sizes, int n_in,
                              void* d_out, int out_size, void* d_ws, size_t ws_size,
                              hipStream_t stream)
{
  (void)in_sizes; (void)n_in; (void)out_size; (void)ws_size;
  const float* hs   = (const float*)d_in[0];
  const float* mask = (const float*)d_in[1];
  const int*   pos  = (const int*)d_in[2];
  const float* qw   = (const float*)d_in[3];
  const float* qb   = (const float*)d_in[4];
  const float* kw   = (const float*)d_in[5];
  const float* kb   = (const float*)d_in[6];
  const float* vw   = (const float*)d_in[7];
  const float* vb   = (const float*)d_in[8];
  const float* ow   = (const float*)d_in[9];
  const float* cosT = (const float*)d_in[10];
  const float* sinT = (const float*)d_in[11];
  float* out = (float*)d_out;

  unsigned short* ws  = (unsigned short*)d_ws;
  unsigned short* hsB = ws;                                   // [4096][2048]
  unsigned short* qwB = hsB + (size_t)TOK * HIDDEN;           // [2048][2048] (qwB|kwB|vwB contiguous)
  unsigned short* kwB = qwB + (size_t)HIDDEN * HIDDEN;        // [512][2048]
  unsigned short* vwB = kwB + (size_t)KVD * HIDDEN;           // [512][2048]
  unsigned short* owB = vwB + (size_t)KVD * HIDDEN;           // [2048][2048]
  unsigned short* qB  = owB + (size_t)HIDDEN * HIDDEN;        // [4096][2048]
  unsigned short* kB  = qB  + (size_t)TOK * HIDDEN;           // [4096][512]
  unsigned short* vTB = kB  + (size_t)TOK * KVD;              // [512][4096]  V transposed
  unsigned short* aoB = vTB + (size_t)KVD * TOK;              // [4096][2048]
  (void)vwB;

  // one fused conversion pass (dst = ws prefix, contiguous & in order)
  cvt_all<<<R4 / 256, 256, 0, stream>>>(hs, qw, kw, vw, ow, ws);

  // merged QKV projection: N=3072 (B = qwB|kwB|vwB contiguous); epilogue routes
  // col<2048 -> qB, col<2560 -> kB, else -> vTB (transposed)
  gemm_nt<<<dim3(TOK/128, 3072/128), 256, 0, stream>>>(
      hsB, qwB, qb, kb, vb, qB, kB, vTB, nullptr, TOK, 3072, HIDDEN, 0);

  // RoPE (q scaled by log2e/sqrt(D); k in [TOK][512] layout)
  {
    int total = TOK * NH * 64 + TOK * NKV * 64;
    rope_kernel<<<total / 256, 256, 0, stream>>>(qB, kB, pos, cosT, sinT);
  }

  // attention: 512 blocks x 256 threads, gld_lds-staged K/V
  attn_kernel<<<dim3(Ss/32, NKV, Bb), 256, 0, stream>>>(qB, kB, vTB, mask, aoB);

  // output projection -> fp32 d_out
  gemm_nt<<<dim3(TOK/128, HIDDEN/128), 256, 0, stream>>>(
      aoB, owB, nullptr, nullptr, nullptr, nullptr, nullptr, nullptr, out, TOK, HIDDEN, HIDDEN, HIDDEN);
}

// Round 25
// 214.866 us; speedup vs baseline: 1.2717x; 1.0051x over previous
//
#include <hip/hip_runtime.h>

#define HIDDEN 2048
#define NH 16
#define NKV 4
#define HD 128
#define Bb 2
#define Ss 2048
#define TOK 4096           // Bb*Ss
#define KVD 512            // NKV*HD
#define LOG2E 1.4426950408889634f
#define QSCALE (0.08838834764831845f * 1.4426950408889634f)   // log2e/sqrt(128)
#define DEFER 11.54f       // 8 nats in log2 units

typedef short short8 __attribute__((ext_vector_type(8)));
typedef float f32x4 __attribute__((ext_vector_type(4)));
typedef float f32x16 __attribute__((ext_vector_type(16)));
typedef unsigned int uint4v __attribute__((ext_vector_type(4)));

#define AS1 __attribute__((address_space(1)))
#define AS3 __attribute__((address_space(3)))

#define BARRIER() asm volatile("s_barrier" ::: "memory")
#define WAITV8()  asm volatile("s_waitcnt vmcnt(8)" ::: "memory")
#define WAITV0()  asm volatile("s_waitcnt vmcnt(0)" ::: "memory")

__device__ __forceinline__ float exp2fast(float x){ return __builtin_amdgcn_exp2f(x); }

__device__ __forceinline__ float bf2f(unsigned short u){
  union { unsigned int i; float f; } x; x.i = ((unsigned int)u) << 16; return x.f;
}
__device__ __forceinline__ unsigned short f2bf(float f){
  union { float f; unsigned int i; } x; x.f = f;
  unsigned int r = x.i + 0x7FFFu + ((x.i >> 16) & 1u);   // RNE
  return (unsigned short)(r >> 16);
}
// pack 2 f32 -> 2 bf16 in one u32 (lo = a, hi = b), RNE
__device__ __forceinline__ unsigned int cvtpk(float a, float b){
  unsigned int r;
  asm("v_cvt_pk_bf16_f32 %0, %1, %2" : "=v"(r) : "v"(a), "v"(b));
  return r;
}
__device__ __forceinline__ void gld_lds16(const void* g, void* l){
  __builtin_amdgcn_global_load_lds((const AS1 void*)g, (AS3 void*)l, 16, 0, 0);
}

// ---------------- fused fp32 -> bf16 conversion of all 5 tensors ----------------
#define R0 2097152   // hs  f4 count
#define R1 3145728   // + qw
#define R2 3407872   // + kw
#define R3 3670016   // + vw
#define R4 4718592   // + ow (total)
__global__ void cvt_all(const float* __restrict__ s0, const float* __restrict__ s1,
                        const float* __restrict__ s2, const float* __restrict__ s3,
                        const float* __restrict__ s4, unsigned short* __restrict__ dst){
  int i = blockIdx.x * 256 + threadIdx.x;     // float4 index, grid exact
  const float* src; int off;
  if      (i < R0){ src = s0; off = 0;  }
  else if (i < R1){ src = s1; off = R0; }
  else if (i < R2){ src = s2; off = R1; }
  else if (i < R3){ src = s3; off = R2; }
  else            { src = s4; off = R3; }
  float4 v = reinterpret_cast<const float4*>(src)[i - off];
  ushort4 o;
  o.x = f2bf(v.x); o.y = f2bf(v.y); o.z = f2bf(v.z); o.w = f2bf(v.w);
  reinterpret_cast<ushort4*>(dst)[i] = o;
}

// ---------------- NT GEMM: C[M,N] = A[M,K] * B[N,K]^T (+bias) ----------------
// 128x128 tile, BK=64, double-buffered LDS with counted vmcnt (T3/T4),
// XOR-swizzled LDS. No XCD swizzle (L3-fit working set; swizzle cost ~2%, m160/R16).
// Epilogue regions (merged QKV projection):
//   Cf non-null           -> f32 out at ldc (O-proj path)
//   else col <  2048      -> CbQ bf16, stride 2048, bias qb
//        col <  2560      -> CbK bf16 at col-2048, stride 512, bias kb
//        col >= 2560      -> vT TRANSPOSED at (col-2560)*TOK+row, bias vb
__global__ __launch_bounds__(256, 2) void gemm_nt(
    const unsigned short* __restrict__ A,
    const unsigned short* __restrict__ Bw,
    const float* __restrict__ qb,          // may be null (no bias)
    const float* __restrict__ kb,
    const float* __restrict__ vb,
    unsigned short* __restrict__ CbQ,
    unsigned short* __restrict__ CbK,
    unsigned short* __restrict__ vT,
    float* __restrict__ Cf,                // f32 out (if non-null)
    int M, int N, int K, int ldc)
{
  __shared__ unsigned short lds[2][2][128*64];   // [buf][A|B][row*64 + elem]
  const int tid  = threadIdx.x;
  const int lane = tid & 63;
  const int w  = tid >> 6;          // wave 0..3
  const int wr = w >> 1, wc = w & 1;
  const int row0 = blockIdx.x * 128;
  const int col0 = blockIdx.y * 128;

  const int fr  = lane & 15;
  const int g16 = lane >> 4;
  const int l8  = lane >> 3;        // staging sub-row 0..7
  const int slot = lane & 7;        // staging 16B slot 0..7

  const f32x4 vzero = {0.f, 0.f, 0.f, 0.f};
  f32x4 acc[4][4];
#pragma unroll
  for (int m = 0; m < 4; m++)
#pragma unroll
    for (int n = 0; n < 4; n++) acc[m][n] = vzero;

  // stage one 128x64 K-tile of A and B into lds[buf] (8 gload_lds/thread)
  auto STAGE = [&](int buf, int kt){
#pragma unroll
    for (int i = 0; i < 4; i++){
      int r = w*32 + i*8 + l8;
      gld_lds16(A  + (size_t)(row0 + r)*K + kt*64 + ((slot ^ (r & 7)) << 3),
                &lds[buf][0][w*2048 + i*512 + lane*8]);
    }
#pragma unroll
    for (int i = 0; i < 4; i++){
      int r = w*32 + i*8 + l8;
      gld_lds16(Bw + (size_t)(col0 + r)*K + kt*64 + ((slot ^ (r & 7)) << 3),
                &lds[buf][1][w*2048 + i*512 + lane*8]);
    }
  };

  const int NT = K >> 6;
  STAGE(0, 0);
  STAGE(1, 1);
  WAITV8();            // tile 0 landed (tile 1 still in flight)
  BARRIER();

  for (int kt = 0; kt < NT; kt++){
    const int cur = kt & 1;
    const unsigned short* Al = &lds[cur][0][0];
    const unsigned short* Bl = &lds[cur][1][0];
#pragma unroll
    for (int ks = 0; ks < 2; ks++){
      short8 af[4], bf[4];
#pragma unroll
      for (int m = 0; m < 4; m++){
        int r = wr*64 + m*16 + fr;
        af[m] = *(const short8*)&Al[r*64 + (((ks*4 + g16) ^ (r & 7)) << 3)];
      }
#pragma unroll
      for (int n = 0; n < 4; n++){
        int r = wc*64 + n*16 + fr;
        bf[n] = *(const short8*)&Bl[r*64 + (((ks*4 + g16) ^ (r & 7)) << 3)];
      }
      __builtin_amdgcn_s_setprio(1);
#pragma unroll
      for (int m = 0; m < 4; m++)
#pragma unroll
        for (int n = 0; n < 4; n++)
          acc[m][n] = __builtin_amdgcn_mfma_f32_16x16x32_bf16(af[m], bf[n], acc[m][n], 0, 0, 0);
      __builtin_amdgcn_s_setprio(0);
    }
    if (kt == NT - 1) break;
    BARRIER();                       // all waves done reading lds[cur]
    if (kt + 2 < NT){
      STAGE(cur, kt + 2);            // refill the buffer just consumed
      WAITV8();                      // tile kt+1's 8 loads complete (kt+2's stay in flight)
    } else {
      WAITV0();                      // last tile's loads complete
    }
    BARRIER();                       // writes visible to all waves
  }

  const int rr = g16 * 4;
#pragma unroll
  for (int n = 0; n < 4; n++){
    int col = col0 + wc*64 + n*16 + fr;
    float bv = 0.f;
    if (qb) bv = (col < 2048) ? qb[col] : (col < 2560 ? kb[col - 2048] : vb[col - 2560]);
    if (Cf){
#pragma unroll
      for (int m = 0; m < 4; m++){
        int row = row0 + wr*64 + m*16 + rr;
#pragma unroll
        for (int r = 0; r < 4; r++)
          Cf[(size_t)(row + r) * ldc + col] = acc[m][n][r] + bv;
      }
    } else if (col < 2048){
#pragma unroll
      for (int m = 0; m < 4; m++){
        int row = row0 + wr*64 + m*16 + rr;
#pragma unroll
        for (int r = 0; r < 4; r++)
          CbQ[(size_t)(row + r) * 2048 + col] = f2bf(acc[m][n][r] + bv);
      }
    } else if (col < 2560){
      int ck = col - 2048;
#pragma unroll
      for (int m = 0; m < 4; m++){
        int row = row0 + wr*64 + m*16 + rr;
#pragma unroll
        for (int r = 0; r < 4; r++)
          CbK[(size_t)(row + r) * 512 + ck] = f2bf(acc[m][n][r] + bv);
      }
    } else {
      int cv = col - 2560;
#pragma unroll
      for (int m = 0; m < 4; m++){
        int row = row0 + wr*64 + m*16 + rr;
        ushort4 pk;
        pk.x = f2bf(acc[m][n][0] + bv); pk.y = f2bf(acc[m][n][1] + bv);
        pk.z = f2bf(acc[m][n][2] + bv); pk.w = f2bf(acc[m][n][3] + bv);
        *reinterpret_cast<ushort4*>(&vT[(size_t)cv * TOK + row]) = pk;
      }
    }
  }
}

// ---------------- RoPE (in-place; q scaled by log2e/sqrt(D)) ----------------
__global__ void rope_kernel(unsigned short* __restrict__ q, unsigned short* __restrict__ k,
                            const int* __restrict__ pos,
                            const float* __restrict__ cosT, const float* __restrict__ sinT)
{
  int idx = blockIdx.x * blockDim.x + threadIdx.x;
  const int qN = TOK * NH * 64;
  if (idx < qN){
    int d  = idx & 63;
    int hh = (idx >> 6) & (NH - 1);
    int t  = idx >> 10;
    int p  = pos[t & (Ss - 1)];
    float c = cosT[p * HD + d], s = sinT[p * HD + d];
    unsigned short* base = q + (size_t)t * HIDDEN + hh * HD;
    float lo = bf2f(base[d]), hi = bf2f(base[d + 64]);
    base[d]      = f2bf((lo * c - hi * s) * QSCALE);
    base[d + 64] = f2bf((hi * c + lo * s) * QSCALE);
  } else {
    int j  = idx - qN;
    int d  = j & 63;
    int hh = (j >> 6) & (NKV - 1);
    int t  = j >> 8;
    int p  = pos[t & (Ss - 1)];
    float c = cosT[p * HD + d], s = sinT[p * HD + d];
    unsigned short* base = k + (size_t)t * KVD + hh * HD;
    float lo = bf2f(base[d]), hi = bf2f(base[d + 64]);
    base[d]      = f2bf(lo * c - hi * s);
    base[d + 64] = f2bf(hi * c + lo * s);
  }
}

// ---------------- Flash attention: swapped-QK 32x32 in-register softmax ----------------
// grid (64,4,2) = 512 blocks; 256 threads = 4 waves = 4 heads x one 32-row q-subtile.
// KVBLK=128: one barrier pair per 128 k (half the barriers of the 64-k version);
// the staged tile is processed in two read-only 64-k passes (registers unchanged).
// K/V staged via global_load_lds (pre-swizzled global src, linear LDS dest, rule #21).
// LDS 64 KB -> 2 blocks/CU (same residency as the VGPR cap: ~116 arch + 64 acc).
__global__ __launch_bounds__(256, 2) void attn_kernel(
    const unsigned short* __restrict__ Q,    // [TOK][HIDDEN], post-RoPE, pre-scaled
    const unsigned short* __restrict__ Kb,   // [TOK][KVD]
    const unsigned short* __restrict__ Vt,   // V^T [KVD][TOK]
    const float* __restrict__ mask,          // [Bb][Ss]
    unsigned short* __restrict__ O)          // [TOK][HIDDEN]
{
  __shared__ unsigned short Klds[128*128];   // [k][16 slots], slot stores global slot^(k&7)
  __shared__ unsigned short Vlds[128*128];   // V^T [d][16 slots], slot stores global slot^(d&7)

  const int tid = threadIdx.x, lane = tid & 63, wid = tid >> 6;
  const int qt = blockIdx.x, kvh = blockIdx.y, b = blockIdx.z;
  const int head = kvh*4 + wid;
  const int q0 = lane & 31;          // this lane's q-row (softmax) / d-col (PV out)
  const int h  = lane >> 5;          // half-wave id
  const int tokQ = b*Ss + qt*32;

  // Q fragments in registers: 8 d-slots of 16 (B-frag: col=q0, k-elems h*8..h*8+7)
  short8 qf[8];
#pragma unroll
  for (int ds = 0; ds < 8; ds++)
    qf[ds] = *(const short8*)(Q + (size_t)(tokQ + q0)*HIDDEN + head*HD + ds*16 + h*8);

  f32x16 oacc[4];
#pragma unroll
  for (int dblk = 0; dblk < 4; dblk++)
#pragma unroll
    for (int r = 0; r < 16; r++) oacc[dblk][r] = 0.f;
  float mrow = -1e30f, lrow = 0.f;

  const float* maskrow = mask + b*Ss;

  // staging lane geometry: 4 rows x 16 slots per wave-call (rows have 16x16B chunks)
  const int rl = lane >> 4, sl = lane & 15;

  const size_t kgbase = (size_t)(b*Ss)*KVD + (size_t)kvh*HD;
  const size_t vgbase = (size_t)(kvh*HD)*TOK + (size_t)(b*Ss);

  const int NT = Ss/128;
  for (int kt = 0; kt < NT; kt++){
    if (kt) __syncthreads();       // all reads of LDS done before overwrite
    const int tok = kt*128;
    // async stage of the 128-k tile: per-lane swizzled global addr, linear LDS dest
#pragma unroll
    for (int i = 0; i < 8; i++){
      int kr = wid*32 + i*4 + rl;
      gld_lds16(Kb + kgbase + (size_t)(tok + kr)*KVD + ((sl ^ (kr & 7)) << 3),
                &Klds[(wid*32 + i*4)*128]);
      int vr = wid*32 + i*4 + rl;
      gld_lds16(Vt + vgbase + (size_t)vr*TOK + tok + ((sl ^ (vr & 7)) << 3),
                &Vlds[(wid*32 + i*4)*128]);
    }
    __syncthreads();               // vmcnt(0) drain + barrier: tile visible

#pragma unroll
    for (int half = 0; half < 2; half++){
      const int kb64 = half*64;

      // ---- S^T = K * Q^T : two 32x32 outputs (k-subtiles), chained over 8 d-slots
      f32x16 st0, st1;
#pragma unroll
      for (int r = 0; r < 16; r++){ st0[r] = 0.f; st1[r] = 0.f; }
      __builtin_amdgcn_s_setprio(1);
#pragma unroll
      for (int ds = 0; ds < 8; ds++){
        short8 kf0 = *(const short8*)&Klds[(kb64 + q0     )*128 + ((ds*16 + h*8) ^ ((q0 & 7) << 3))];
        short8 kf1 = *(const short8*)&Klds[(kb64 + 32 + q0)*128 + ((ds*16 + h*8) ^ ((q0 & 7) << 3))];
        st0 = __builtin_amdgcn_mfma_f32_32x32x16_bf16(kf0, qf[ds], st0, 0, 0, 0);
        st1 = __builtin_amdgcn_mfma_f32_32x32x16_bf16(kf1, qf[ds], st1, 0, 0, 0);
      }
      __builtin_amdgcn_s_setprio(0);

      // ---- mask add (log2 domain); p[t*16+reg], k = 32t + (reg&3)+8*(reg>>2)+4h
      float p[32];
#pragma unroll
      for (int g2 = 0; g2 < 4; g2++){
        f32x4 m0 = *(const f32x4*)(maskrow + tok + kb64      + g2*8 + h*4);
        f32x4 m1 = *(const f32x4*)(maskrow + tok + kb64 + 32 + g2*8 + h*4);
#pragma unroll
        for (int r = 0; r < 4; r++){
          p[g2*4 + r]      = st0[g2*4 + r] + m0[r] * LOG2E;
          p[16 + g2*4 + r] = st1[g2*4 + r] + m1[r] * LOG2E;
        }
      }

      // ---- online softmax (in-register; row is lane-local, 1 cross-lane op)
      float vmax = p[0];
#pragma unroll
      for (int i = 1; i < 32; i++) vmax = fmaxf(vmax, p[i]);
      vmax = fmaxf(vmax, __shfl_xor(vmax, 32));
      if (__any(vmax > mrow + DEFER)){
        float mnew = fmaxf(mrow, vmax);
        float sc = exp2fast(mrow - mnew);
        mrow = mnew; lrow *= sc;
#pragma unroll
        for (int reg = 0; reg < 16; reg++){
          float scr = __shfl(sc, (reg & 3) + 8*(reg >> 2) + 4*h);
#pragma unroll
          for (int dblk = 0; dblk < 4; dblk++) oacc[dblk][reg] *= scr;
        }
      }
      float rs = 0.f;
#pragma unroll
      for (int i = 0; i < 32; i++){ p[i] = exp2fast(p[i] - mrow); rs += p[i]; }
      rs += __shfl_xor(rs, 32);
      lrow += rs;

      // ---- pack P to bf16 and build PV A-frags via one shfl_xor(32) exchange
      unsigned int pk[8][2];
#pragma unroll
      for (int G = 0; G < 8; G++){
        pk[G][0] = cvtpk(p[G*4 + 0], p[G*4 + 1]);
        pk[G][1] = cvtpk(p[G*4 + 2], p[G*4 + 3]);
      }
      short8 pa[4];
#pragma unroll
      for (int ks = 0; ks < 4; ks++){
        const int ia = 4*(ks >> 1) + 2*(ks & 1);
        unsigned int A0 = pk[ia][0],   A1 = pk[ia][1];
        unsigned int B0 = pk[ia+1][0], B1 = pk[ia+1][1];
        unsigned int s0 = h ? A0 : B0, s1 = h ? A1 : B1;
        unsigned int r0 = (unsigned int)__shfl_xor((int)s0, 32);
        unsigned int r1 = (unsigned int)__shfl_xor((int)s1, 32);
        uint4v wv = { h ? r0 : A0, h ? r1 : A1, h ? B0 : r0, h ? B1 : r1 };
        pa[ks] = __builtin_bit_cast(short8, wv);
      }

      // ---- O += P * V  (A = pa[ks], B = V^T fragments from LDS)
      __builtin_amdgcn_s_setprio(1);
#pragma unroll
      for (int dblk = 0; dblk < 4; dblk++){
#pragma unroll
        for (int ks = 0; ks < 4; ks++){
          short8 vb = *(const short8*)&Vlds[(dblk*32 + q0)*128 + ((kb64 + ks*16 + h*8) ^ ((q0 & 7) << 3))];
          oacc[dblk] = __builtin_amdgcn_mfma_f32_32x32x16_bf16(pa[ks], vb, oacc[dblk], 0, 0, 0);
        }
      }
      __builtin_amdgcn_s_setprio(0);
    }
  }

  // ---- epilogue: O[q = crow(reg,h)][d = dblk*32 + q0]
  float inv = 1.0f / lrow;
#pragma unroll
  for (int reg = 0; reg < 16; reg++){
    const int crow = (reg & 3) + 8*(reg >> 2) + 4*h;
    float invr = __shfl(inv, crow);
    int row = tokQ + crow;
#pragma unroll
    for (int dblk = 0; dblk < 4; dblk++)
      O[(size_t)row*HIDDEN + head*HD + dblk*32 + q0] = f2bf(oacc[dblk][reg] * invr);
  }
}

// ---------------- launcher ----------------
extern "C" void kernel_launch(void* const* d_in, const int* in_sizes, int n_in,
                              void* d_out, int out_size, void* d_ws, size_t ws_size,
                              hipStream_t stream)
{
  (void)in_sizes; (void)n_in; (void)out_size; (void)ws_size;
  const float* hs   = (const float*)d_in[0];
  const float* mask = (const float*)d_in[1];
  const int*   pos  = (const int*)d_in[2];
  const float* qw   = (const float*)d_in[3];
  const float* qb   = (const float*)d_in[4];
  const float* kw   = (const float*)d_in[5];
  const float* kb   = (const float*)d_in[6];
  const float* vw   = (const float*)d_in[7];
  const float* vb   = (const float*)d_in[8];
  const float* ow   = (const float*)d_in[9];
  const float* cosT = (const float*)d_in[10];
  const float* sinT = (const float*)d_in[11];
  float* out = (float*)d_out;

  unsigned short* ws  = (unsigned short*)d_ws;
  unsigned short* hsB = ws;                                   // [4096][2048]
  unsigned short* qwB = hsB + (size_t)TOK * HIDDEN;           // [2048][2048] (qwB|kwB|vwB contiguous)
  unsigned short* kwB = qwB + (size_t)HIDDEN * HIDDEN;        // [512][2048]
  unsigned short* vwB = kwB + (size_t)KVD * HIDDEN;           // [512][2048]
  unsigned short* owB = vwB + (size_t)KVD * HIDDEN;           // [2048][2048]
  unsigned short* qB  = owB + (size_t)HIDDEN * HIDDEN;        // [4096][2048]
  unsigned short* kB  = qB  + (size_t)TOK * HIDDEN;           // [4096][512]
  unsigned short* vTB = kB  + (size_t)TOK * KVD;              // [512][4096]  V transposed
  unsigned short* aoB = vTB + (size_t)KVD * TOK;              // [4096][2048]
  (void)vwB;

  // one fused conversion pass (dst = ws prefix, contiguous & in order)
  cvt_all<<<R4 / 256, 256, 0, stream>>>(hs, qw, kw, vw, ow, ws);

  // merged QKV projection: N=3072 (B = qwB|kwB|vwB contiguous); epilogue routes
  // col<2048 -> qB, col<2560 -> kB, else -> vTB (transposed)
  gemm_nt<<<dim3(TOK/128, 3072/128), 256, 0, stream>>>(
      hsB, qwB, qb, kb, vb, qB, kB, vTB, nullptr, TOK, 3072, HIDDEN, 0);

  // RoPE (q scaled by log2e/sqrt(D); k in [TOK][512] layout)
  {
    int total = TOK * NH * 64 + TOK * NKV * 64;
    rope_kernel<<<total / 256, 256, 0, stream>>>(qB, kB, pos, cosT, sinT);
  }

  // attention: 512 blocks x 256 threads, KVBLK=128 (half the barriers)
  attn_kernel<<<dim3(Ss/32, NKV, Bb), 256, 0, stream>>>(qB, kB, vTB, mask, aoB);

  // output projection -> fp32 d_out
  gemm_nt<<<dim3(TOK/128, HIDDEN/128), 256, 0, stream>>>(
      aoB, owB, nullptr, nullptr, nullptr, nullptr, nullptr, nullptr, out, TOK, HIDDEN, HIDDEN, HIDDEN);
}